// Round 8
// baseline (106.319 us; speedup 1.0000x reference)
//
#include <hip/hip_runtime.h>

#define N 2000
#define NCLS 21
#define MAXPC 50
#define MAXPI 100
#define IOU_THR 0.7f
#define RPW 125              // rows per wave: 16 waves * 125 = 2000

typedef unsigned long long u64;
typedef unsigned int u32;

// monotone float -> uint32 map (order-preserving, incl. negatives)
__device__ __forceinline__ u32 sortable(float s) {
    u32 u = __float_as_uint(s);
    return ((int)u < 0) ? ~u : (u | 0x80000000u);
}

// decode one box on the fly (bit-identical to reference formula)
__device__ __forceinline__ float4 decode_one(const float* __restrict__ rpn,
                                             const float* __restrict__ deltas, int i) {
    float4 p = ((const float4*)rpn)[i];
    float4 d = ((const float4*)deltas)[i];
    float h = p.z - p.x, w = p.w - p.y;
    float cy = p.x + 0.5f * h, cx = p.y + 0.5f * w;
    float pcy = d.x * h + cy;
    float pcx = d.y * w + cx;
    float ph = h * expf(d.z);
    float pw = w * expf(d.w);
    return make_float4(pcy - 0.5f * ph, pcx - 0.5f * pw, pcy + 0.5f * ph, pcx + 0.5f * pw);
}

__device__ __forceinline__ float iou_vs(float4 b, float ar,
                                        float kx, float ky, float kz, float kw) {
    float ka = (kz - kx) * (kw - ky);
    float iy1 = fmaxf(b.x, kx), ix1 = fmaxf(b.y, ky);
    float iy2 = fminf(b.z, kz), ix2 = fminf(b.w, kw);
    float inter = fmaxf(iy2 - iy1, 0.f) * fmaxf(ix2 - ix1, 0.f);
    return inter / fmaxf(ar + ka - inter, 1e-8f);
}

// ONE launch, 21 blocks (one per class, 1024 threads):
//  P1: intra-block stable sort (register-tiled rank count, broadcast LDS scan)
//  P2: greedy NMS on wave 0 (register kept-list)
//  P3: 21 release-adds on `done`; winner (old%21==20 -> exactly one per launch,
//      any start value) acquires and runs binary-search top-100 with 1024 thr.
// Only 21 device-scope RMWs total (r7's 672 cost ~55us of serialization).
__global__ void __launch_bounds__(1024, 1)
fused_kernel(const float* __restrict__ rpn, const float* __restrict__ deltas,
             const float* __restrict__ score,
             int* __restrict__ order, int* __restrict__ keep_pos,
             int* __restrict__ keep_cnt, u64* __restrict__ cand_key,
             u32* __restrict__ done,        // persistent counter, never reset
             float* __restrict__ out) {
    __shared__ __align__(16) u64 sk[N];     // P1: row keys; P3 (winner): cand keys
    __shared__ int sorder[N];               // sorted order for this class
    __shared__ int scnt[NCLS];
    __shared__ int s_flag;

    int c = blockIdx.x;
    int tid = threadIdx.x;

    // ---------- stage keys: key = (sortable(score)<<32) | ~i ----------
    for (int i = tid; i < N; i += 1024) {
        u32 u = sortable(score[i * NCLS + c]);
        sk[i] = ((u64)u << 32) | (u32)(~i);
    }
    __syncthreads();

    // ---------- Phase 1: stable descending sort (rank counting) ----------
    // Wave w owns rows [w*125, w*125+125). Lane l: half=l>>5 scans half the
    // j-range; rs=l&31 owns rows rs, rs+32, rs+64, rs+96 (last masked).
    // All lanes of a half read the SAME LDS address -> broadcast, 2-way = free.
    {
        int l = tid & 63;
        int half = l >> 5, rs = l & 31;
        int base = (tid >> 6) * RPW;
        bool v3 = rs + 96 < RPW;                  // rows 0..2 always valid
        u64 k0 = sk[base + rs];
        u64 k1 = sk[base + rs + 32];
        u64 k2 = sk[base + rs + 64];
        u64 k3 = v3 ? sk[base + rs + 96] : 0;
        int r0 = 0, r1 = 0, r2 = 0, r3 = 0;
        const ulonglong2* s2 = (const ulonglong2*)sk;
        int jb = half * (N / 4);                  // 500 ulonglong2 per half
#pragma unroll 2
        for (int jj = 0; jj < N / 4; jj++) {
            ulonglong2 v = s2[jb + jj];
            r0 += (v.x > k0) + (v.y > k0);
            r1 += (v.x > k1) + (v.y > k1);
            r2 += (v.x > k2) + (v.y > k2);
            r3 += (v.x > k3) + (v.y > k3);
        }
        r0 += __shfl_xor(r0, 32);
        r1 += __shfl_xor(r1, 32);
        r2 += __shfl_xor(r2, 32);
        r3 += __shfl_xor(r3, 32);
        if (half == 0) {
            sorder[r0] = base + rs;      order[c * N + r0] = base + rs;
            sorder[r1] = base + rs + 32; order[c * N + r1] = base + rs + 32;
            sorder[r2] = base + rs + 64; order[c * N + r2] = base + rs + 64;
            if (v3) { sorder[r3] = base + rs + 96; order[c * N + r3] = base + rs + 96; }
        }
    }
    __syncthreads();

    // ---------- Phase 2: greedy NMS, wave 0 only, register kept-list ----------
    if (tid < 64) {
        int lane = tid;
        float4 kb = make_float4(0.f, 0.f, 0.f, 0.f);   // kept box held in lane 'nk'
        int nk = 0;
        const int NCH = (N + 63) / 64;
        for (int chunk = 0; chunk < NCH && nk < MAXPC; chunk++) {
            int pos = chunk * 64 + lane;
            bool valid = pos < N;
            int oi = valid ? sorder[pos] : 0;
            float4 bb = decode_one(rpn, deltas, oi);
            float ar = (bb.z - bb.x) * (bb.w - bb.y);
            bool sup = !valid;
            for (int k = 0; k < nk; k++) {             // vs already-kept (shfl bcast)
                float kx = __shfl(kb.x, k), ky = __shfl(kb.y, k);
                float kz = __shfl(kb.z, k), kw = __shfl(kb.w, k);
                sup = sup || (iou_vs(bb, ar, kx, ky, kz, kw) > IOU_THR);
            }
            u64 alive = __ballot(!sup);
            while (alive && nk < MAXPC) {              // in-wave greedy resolve
                int l = __ffsll((unsigned long long)alive) - 1;
                float bxx = __shfl(bb.x, l), bxy = __shfl(bb.y, l);
                float bxz = __shfl(bb.z, l), bxw = __shfl(bb.w, l);
                if (lane == nk) kb = make_float4(bxx, bxy, bxz, bxw);
                if (lane == l) {
                    keep_pos[c * MAXPC + nk] = pos;
                    u32 hi = (u32)(sk[oi] >> 32);      // score key from LDS
                    cand_key[c * MAXPC + nk] = ((u64)hi << 32) | (u32)(~(c * N + pos));
                }
                nk++;
                if (lane > l && !sup)
                    sup = (iou_vs(bb, ar, bxx, bxy, bxz, bxw) > IOU_THR);
                u64 nb = __ballot(!sup);
                alive = (l >= 63) ? 0ull : (nb & (~0ull << (l + 1)));
            }
        }
        if (lane == 0) keep_cnt[c] = nk;
    }
    __syncthreads();                        // all waves: NMS global stores drained

    // ---------- Phase 3: last class to finish runs top-100 ----------
    if (tid == 0) {
        // release: this block's order/cand/keep stores written back first
        u32 old = __hip_atomic_fetch_add(done, 1u, __ATOMIC_RELEASE,
                                         __HIP_MEMORY_SCOPE_AGENT);
        s_flag = ((old % 21u) == 20u);      // exactly one winner per launch
    }
    __syncthreads();
    if (!s_flag) return;
    __builtin_amdgcn_fence(__ATOMIC_ACQUIRE, "agent");  // see all blocks' output

    // stage all candidate keys (reuse sk) + counts
    for (int t = tid; t < NCLS * MAXPC; t += 1024)
        sk[t] = cand_key[t];
    if (tid < NCLS) scnt[tid] = keep_cnt[tid];
    __syncthreads();
    int M = 0;
#pragma unroll
    for (int c2 = 0; c2 < NCLS; c2++) M += scnt[c2];

    for (int t = tid; t < NCLS * MAXPC; t += 1024) {
        int cc = t / MAXPC, k = t - cc * MAXPC;
        if (k >= scnt[cc]) continue;
        u64 ki = sk[t];
        int r = k;                           // rank within own descending list
#pragma unroll
        for (int c2 = 0; c2 < NCLS; c2++) {
            if (c2 == cc) continue;
            int lo = 0, hi = scnt[c2];
            while (lo < hi) {                // count of keys[c2][*] > ki
                int mid = (lo + hi) >> 1;
                if (sk[c2 * MAXPC + mid] > ki) lo = mid + 1; else hi = mid;
            }
            r += lo;
        }
        if (r < MAXPI) {
            int flat = (int)(~(u32)ki);
            int pos = flat - cc * N;
            int oi = order[cc * N + pos];
            float4 bb = decode_one(rpn, deltas, oi);
            out[r * 4 + 0] = bb.x;
            out[r * 4 + 1] = bb.y;
            out[r * 4 + 2] = bb.z;
            out[r * 4 + 3] = bb.w;
            out[4 * MAXPI + r] = (float)cc;
        }
    }
    // rare path: M<100 -> fill with NEG entries, smallest flat first (class 0
    // positions; among pos 0..149 at most 50 kept -> >=100 invalid slots).
    if (tid == 0 && M < MAXPI) {
        int m = M;
        int cnt0 = scnt[0];
        for (int pos = 0; pos < 150 && m < MAXPI; pos++) {
            bool validp = false;
            for (int k = 0; k < cnt0; k++)
                if (keep_pos[k] == pos) { validp = true; break; }
            if (!validp) {
                int oi = order[pos];
                float4 bb = decode_one(rpn, deltas, oi);
                out[m * 4 + 0] = bb.x;
                out[m * 4 + 1] = bb.y;
                out[m * 4 + 2] = bb.z;
                out[m * 4 + 3] = bb.w;
                out[4 * MAXPI + m] = 0.0f;
                m++;
            }
        }
    }
}

extern "C" void kernel_launch(void* const* d_in, const int* in_sizes, int n_in,
                              void* d_out, int out_size, void* d_ws, size_t ws_size,
                              hipStream_t stream) {
    const float* rpn    = (const float*)d_in[0];  // [2000,4]
    const float* deltas = (const float*)d_in[1];  // [2000,4]
    const float* score  = (const float*)d_in[2];  // [2000,21]
    float* out = (float*)d_out;                   // 400 box floats + 100 cls

    char* ws = (char*)d_ws;
    int*   order    = (int*)(ws);                 // 168000 B
    u64*   candk    = (u64*)(ws + 168000);        // 8400 B (8-aligned)
    int*   keep_pos = (int*)(ws + 176400);        // 4200 B
    int*   keep_cnt = (int*)(ws + 180600);        // 84 B
    u32*   done     = (u32*)(ws + 180736);        // persistent counter (mod-21 window
                                                  // logic -> no reset dispatch needed)

    fused_kernel<<<NCLS, 1024, 0, stream>>>(rpn, deltas, score, order,
                                            keep_pos, keep_cnt, candk, done, out);
}

// Round 9
// 54.581 us; speedup vs baseline: 1.9479x; 1.9479x over previous
//
#include <hip/hip_runtime.h>

#define N 2000
#define NCLS 21
#define MAXPC 50
#define MAXPI 100
#define IOU_THR 0.7f

typedef unsigned long long u64;
typedef unsigned int u32;

// monotone float -> uint32 map (order-preserving, incl. negatives)
__device__ __forceinline__ u32 sortable(float s) {
    u32 u = __float_as_uint(s);
    return ((int)u < 0) ? ~u : (u | 0x80000000u);
}

// decode one box on the fly (bit-identical to reference formula)
__device__ __forceinline__ float4 decode_one(const float* __restrict__ rpn,
                                             const float* __restrict__ deltas, int i) {
    float4 p = ((const float4*)rpn)[i];
    float4 d = ((const float4*)deltas)[i];
    float h = p.z - p.x, w = p.w - p.y;
    float cy = p.x + 0.5f * h, cx = p.y + 0.5f * w;
    float pcy = d.x * h + cy;
    float pcx = d.y * w + cx;
    float ph = h * expf(d.z);
    float pw = w * expf(d.w);
    return make_float4(pcy - 0.5f * ph, pcx - 0.5f * pw, pcy + 0.5f * ph, pcx + 0.5f * pw);
}

__device__ __forceinline__ float iou_vs(float4 b, float ar,
                                        float kx, float ky, float kz, float kw) {
    float ka = (kz - kx) * (kw - ky);
    float iy1 = fmaxf(b.x, kx), ix1 = fmaxf(b.y, ky);
    float iy2 = fminf(b.z, kz), ix2 = fminf(b.w, kw);
    float inter = fmaxf(iy2 - iy1, 0.f) * fmaxf(ix2 - ix1, 0.f);
    return inter / fmaxf(ar + ka - inter, 1e-8f);
}

// ---------------- Launch A: spread stable sort (r4-proven) ----------------
// 672 blocks over 256 CUs: device VALU floor ~3-5us for the 84M u64 compares
// (u64 cmp is half-rate; concentrating on 21 CUs costs ~50us -- r8 lesson).
__global__ void sort_kernel(const float* __restrict__ score, int* __restrict__ order) {
    __shared__ __align__(16) u64 skey[N];
    int c = blockIdx.x;
    for (int i = threadIdx.x; i < N; i += blockDim.x) {
        u32 u = sortable(score[i * NCLS + c]);
        skey[i] = ((u64)u << 32) | (u32)(~i);
    }
    __syncthreads();
    int i = blockIdx.y * 64 + (threadIdx.x >> 2);
    int q = threadIdx.x & 3;
    if (i < N) {
        u64 ki = skey[i];
        const ulonglong2* s2 = (const ulonglong2*)skey;
        int r = 0;
        int jj0 = q * 250;
#pragma unroll 4
        for (int jj = jj0; jj < jj0 + 250; jj++) {
            ulonglong2 v = s2[jj];
            r += (v.x > ki);
            r += (v.y > ki);
        }
        r += __shfl_xor(r, 1);
        r += __shfl_xor(r, 2);
        if (q == 0) order[c * N + r] = i;
    }
}

// ---------------- Launch B: fused NMS + top-100 ----------------
// 21 blocks x 1024. Stage decoded boxes + score keys into LDS with 16 waves
// (parallel gather), NMS on wave 0 touches LDS only, then 21 release-RMWs on
// `done`; winner (old%21==20 -> exactly one per launch, any start value,
// no reset dispatch) acquires and runs binary-search top-100.
__global__ void __launch_bounds__(1024, 1)
nms_topk_kernel(const float* __restrict__ rpn, const float* __restrict__ deltas,
                const float* __restrict__ score,
                const int* __restrict__ order,
                int* __restrict__ keep_pos, int* __restrict__ keep_cnt,
                u64* __restrict__ cand_key,
                u32* __restrict__ done,          // persistent counter, never reset
                float* __restrict__ out) {
    __shared__ __align__(16) float4 sbox[N];     // decoded boxes, sorted order (32 KB)
    __shared__ u32 skey[N];                      // score keys, sorted order (8 KB)
    __shared__ float4 kbox[MAXPC];
    __shared__ u64 tk[NCLS * MAXPC];             // winner: staged cand keys (8.4 KB)
    __shared__ int scnt[NCLS];
    __shared__ int s_flag;

    int c = blockIdx.x;
    int tid = threadIdx.x;

    // ---------- stage: decode all boxes in sorted order ----------
    for (int pos = tid; pos < N; pos += 1024) {
        int oi = order[c * N + pos];
        sbox[pos] = decode_one(rpn, deltas, oi);
        skey[pos] = sortable(score[oi * NCLS + c]);
    }
    __syncthreads();

    // ---------- NMS on wave 0, LDS-only ----------
    if (tid < 64) {
        int lane = tid;
        int nk = 0;
        const int NCH = (N + 63) / 64;
        for (int chunk = 0; chunk < NCH && nk < MAXPC; chunk++) {
            int pos = chunk * 64 + lane;
            bool valid = pos < N;
            float4 bb = sbox[valid ? pos : (N - 1)];
            float ar = (bb.z - bb.x) * (bb.w - bb.y);
            bool sup = !valid;
            for (int k = 0; k < nk; k++) {       // vs kept: uniform LDS read = broadcast
                float4 kb = kbox[k];
                sup = sup || (iou_vs(bb, ar, kb.x, kb.y, kb.z, kb.w) > IOU_THR);
            }
            u64 alive = __ballot(!sup);
            while (alive && nk < MAXPC) {        // in-wave greedy resolve
                int l = __ffsll((unsigned long long)alive) - 1;
                if (lane == l) {
                    kbox[nk] = bb;
                    keep_pos[c * MAXPC + nk] = pos;
                    cand_key[c * MAXPC + nk] =
                        ((u64)skey[pos] << 32) | (u32)(~(c * N + pos));
                }
                float4 nbx = kbox[nk];           // uniform read after lane-l write
                nk++;
                if (lane > l && !sup)
                    sup = (iou_vs(bb, ar, nbx.x, nbx.y, nbx.z, nbx.w) > IOU_THR);
                u64 nb = __ballot(!sup);
                alive = (l >= 63) ? 0ull : (nb & (~0ull << (l + 1)));
            }
        }
        if (lane == 0) keep_cnt[c] = nk;
    }
    __syncthreads();                             // all waves: global stores drained

    // ---------- last class to finish runs top-100 ----------
    if (tid == 0) {
        u32 old = __hip_atomic_fetch_add(done, 1u, __ATOMIC_RELEASE,
                                         __HIP_MEMORY_SCOPE_AGENT);
        s_flag = ((old % 21u) == 20u);           // exactly one winner per launch
    }
    __syncthreads();
    if (!s_flag) return;
    __builtin_amdgcn_fence(__ATOMIC_ACQUIRE, "agent");   // see all blocks' output

    for (int t = tid; t < NCLS * MAXPC; t += 1024)
        tk[t] = cand_key[t];
    if (tid < NCLS) scnt[tid] = keep_cnt[tid];
    __syncthreads();
    int M = 0;
#pragma unroll
    for (int c2 = 0; c2 < NCLS; c2++) M += scnt[c2];

    for (int t = tid; t < NCLS * MAXPC; t += 1024) {
        int cc = t / MAXPC, k = t - cc * MAXPC;
        if (k >= scnt[cc]) continue;
        u64 ki = tk[t];
        int r = k;                               // rank within own descending list
#pragma unroll
        for (int c2 = 0; c2 < NCLS; c2++) {
            if (c2 == cc) continue;
            int lo = 0, hi = scnt[c2];
            while (lo < hi) {                    // count of keys[c2][*] > ki
                int mid = (lo + hi) >> 1;
                if (tk[c2 * MAXPC + mid] > ki) lo = mid + 1; else hi = mid;
            }
            r += lo;
        }
        if (r < MAXPI) {
            int flat = (int)(~(u32)ki);
            int pos = flat - cc * N;
            int oi = order[cc * N + pos];
            float4 bb = decode_one(rpn, deltas, oi);
            out[r * 4 + 0] = bb.x;
            out[r * 4 + 1] = bb.y;
            out[r * 4 + 2] = bb.z;
            out[r * 4 + 3] = bb.w;
            out[4 * MAXPI + r] = (float)cc;
        }
    }
    // rare path: M<100 -> fill with NEG entries, smallest flat first (class 0
    // positions; among pos 0..149 at most 50 kept -> >=100 invalid slots).
    if (tid == 0 && M < MAXPI) {
        int m = M;
        int cnt0 = scnt[0];
        for (int pos = 0; pos < 150 && m < MAXPI; pos++) {
            bool validp = false;
            for (int k = 0; k < cnt0; k++)
                if (keep_pos[k] == pos) { validp = true; break; }
            if (!validp) {
                int oi = order[pos];
                float4 bb = decode_one(rpn, deltas, oi);
                out[m * 4 + 0] = bb.x;
                out[m * 4 + 1] = bb.y;
                out[m * 4 + 2] = bb.z;
                out[m * 4 + 3] = bb.w;
                out[4 * MAXPI + m] = 0.0f;
                m++;
            }
        }
    }
}

extern "C" void kernel_launch(void* const* d_in, const int* in_sizes, int n_in,
                              void* d_out, int out_size, void* d_ws, size_t ws_size,
                              hipStream_t stream) {
    const float* rpn    = (const float*)d_in[0];  // [2000,4]
    const float* deltas = (const float*)d_in[1];  // [2000,4]
    const float* score  = (const float*)d_in[2];  // [2000,21]
    float* out = (float*)d_out;                   // 400 box floats + 100 cls

    char* ws = (char*)d_ws;
    int*   order    = (int*)(ws);                 // 168000 B
    u64*   candk    = (u64*)(ws + 168000);        // 8400 B (8-aligned)
    int*   keep_pos = (int*)(ws + 176400);        // 4200 B
    int*   keep_cnt = (int*)(ws + 180600);        // 84 B
    u32*   done     = (u32*)(ws + 180736);        // persistent counter (mod-21 winner
                                                  // logic -> no reset dispatch needed)

    sort_kernel<<<dim3(NCLS, 32), 256, 0, stream>>>(score, order);
    nms_topk_kernel<<<NCLS, 1024, 0, stream>>>(rpn, deltas, score, order,
                                               keep_pos, keep_cnt, candk, done, out);
}

// Round 10
// 53.756 us; speedup vs baseline: 1.9778x; 1.0153x over previous
//
#include <hip/hip_runtime.h>

#define N 2000
#define NCLS 21
#define MAXPC 50
#define MAXPI 100
#define IOU_THR 0.7f

typedef unsigned long long u64;
typedef unsigned int u32;

// monotone float -> uint32 map (order-preserving, incl. negatives)
__device__ __forceinline__ u32 sortable(float s) {
    u32 u = __float_as_uint(s);
    return ((int)u < 0) ? ~u : (u | 0x80000000u);
}

// decode one box on the fly (bit-identical to reference formula)
__device__ __forceinline__ float4 decode_one(const float* __restrict__ rpn,
                                             const float* __restrict__ deltas, int i) {
    float4 p = ((const float4*)rpn)[i];
    float4 d = ((const float4*)deltas)[i];
    float h = p.z - p.x, w = p.w - p.y;
    float cy = p.x + 0.5f * h, cx = p.y + 0.5f * w;
    float pcy = d.x * h + cy;
    float pcx = d.y * w + cx;
    float ph = h * expf(d.z);
    float pw = w * expf(d.w);
    return make_float4(pcy - 0.5f * ph, pcx - 0.5f * pw, pcy + 0.5f * ph, pcx + 0.5f * pw);
}

__device__ __forceinline__ float iou_vs(float4 b, float ar,
                                        float kx, float ky, float kz, float kw) {
    float ka = (kz - kx) * (kw - ky);
    float iy1 = fmaxf(b.x, kx), ix1 = fmaxf(b.y, ky);
    float iy2 = fminf(b.z, kz), ix2 = fminf(b.w, kw);
    float inter = fmaxf(iy2 - iy1, 0.f) * fmaxf(ix2 - ix1, 0.f);
    return inter / fmaxf(ar + ka - inter, 1e-8f);
}

// ---------------- K1: spread stable sort (r4-proven) ----------------
__global__ void sort_kernel(const float* __restrict__ score, int* __restrict__ order) {
    __shared__ __align__(16) u64 skey[N];
    int c = blockIdx.x;
    for (int i = threadIdx.x; i < N; i += blockDim.x) {
        u32 u = sortable(score[i * NCLS + c]);
        skey[i] = ((u64)u << 32) | (u32)(~i);
    }
    __syncthreads();
    int i = blockIdx.y * 64 + (threadIdx.x >> 2);
    int q = threadIdx.x & 3;
    if (i < N) {
        u64 ki = skey[i];
        const ulonglong2* s2 = (const ulonglong2*)skey;
        int r = 0;
        int jj0 = q * 250;
#pragma unroll 4
        for (int jj = jj0; jj < jj0 + 250; jj++) {
            ulonglong2 v = s2[jj];
            r += (v.x > ki);
            r += (v.y > ki);
        }
        r += __shfl_xor(r, 1);
        r += __shfl_xor(r, 2);
        if (q == 0) order[c * N + r] = i;
    }
}

// ---------------- K2: greedy NMS, bitmask resolve, 1 wave/class ----------------
// Per 64-chunk: build supby[lane] = bitmask{j : IoU(lane,j)>thr} via uniform
// LDS broadcast reads, then greedy = uniform register loop (1 ballot/step,
// no LDS dependency chain). Equivalent to sequential greedy: kept(i) iff no
// kept j<i with IoU>thr; suppression doesn't cascade.
__global__ void nms_kernel(const float* __restrict__ rpn,
                           const float* __restrict__ deltas,
                           const int* __restrict__ order,
                           const float* __restrict__ score,
                           int* __restrict__ keep_pos,   // [NCLS][MAXPC]
                           int* __restrict__ keep_cnt,   // [NCLS]
                           u64* __restrict__ cand_key) { // [NCLS][MAXPC]
    __shared__ float4 cbox[64];      // current chunk boxes
    __shared__ float4 kbox[MAXPC];   // kept boxes
    int c = blockIdx.x;
    int lane = threadIdx.x;
    int nk = 0;
    const int NCH = (N + 63) / 64;
    for (int chunk = 0; chunk < NCH && nk < MAXPC; chunk++) {
        int pos = chunk * 64 + lane;
        bool valid = pos < N;
        int oi = order[c * N + (valid ? pos : (N - 1))];
        float4 bb = decode_one(rpn, deltas, oi);
        cbox[lane] = bb;
        float ar = (bb.z - bb.x) * (bb.w - bb.y);
        bool sup = !valid;
        for (int k = 0; k < nk; k++) {          // vs kept: uniform LDS read = bcast
            float4 kb = kbox[k];
            sup = sup || (iou_vs(bb, ar, kb.x, kb.y, kb.z, kb.w) > IOU_THR);
        }
        // intra-chunk pairwise suppression bits
        u64 supby = 0;
#pragma unroll 4
        for (int j = 0; j < 64; j++) {          // uniform LDS read = broadcast
            float4 bj = cbox[j];
            supby |= (u64)(iou_vs(bb, ar, bj.x, bj.y, bj.z, bj.w) > IOU_THR) << j;
        }
        u64 alive = __ballot(!sup);
        // uniform greedy over the chunk (all values wave-uniform)
        for (int l = 0; l < 64 && nk < MAXPC; l++) {
            u64 col = __ballot((supby >> l) & 1);       // who l suppresses
            if ((alive >> l) & 1) {
                if (lane == l) {
                    kbox[nk] = bb;
                    keep_pos[c * MAXPC + nk] = pos;
                    u32 u = sortable(score[oi * NCLS + c]);
                    cand_key[c * MAXPC + nk] = ((u64)u << 32) | (u32)(~(c * N + pos));
                }
                nk++;
                alive &= ~(col & (~0ull << (l + 1)));   // drop later ones l suppresses
            }
        }
    }
    if (lane == 0) keep_cnt[c] = nk;
}

// ---------------- K3: top-100, ONE block (kernel boundary = sync) ----------
__global__ void __launch_bounds__(1024, 1)
topk_kernel(const float* __restrict__ rpn, const float* __restrict__ deltas,
            const int* __restrict__ order,
            const int* __restrict__ keep_pos, const int* __restrict__ keep_cnt,
            const u64* __restrict__ cand_key,
            float* __restrict__ out) {
    __shared__ u64 tk[NCLS * MAXPC];
    __shared__ int scnt[NCLS];
    int tid = threadIdx.x;
    for (int t = tid; t < NCLS * MAXPC; t += 1024)
        tk[t] = cand_key[t];                 // stale slots never read (guarded below)
    if (tid < NCLS) scnt[tid] = keep_cnt[tid];
    __syncthreads();
    int M = 0;
#pragma unroll
    for (int c2 = 0; c2 < NCLS; c2++) M += scnt[c2];

    for (int t = tid; t < NCLS * MAXPC; t += 1024) {
        int cc = t / MAXPC, k = t - cc * MAXPC;
        if (k >= scnt[cc]) continue;
        u64 ki = tk[t];
        int r = k;                           // rank within own descending list
#pragma unroll
        for (int c2 = 0; c2 < NCLS; c2++) {
            if (c2 == cc) continue;
            int lo = 0, hi = scnt[c2];
            while (lo < hi) {                // count of keys[c2][*] > ki
                int mid = (lo + hi) >> 1;
                if (tk[c2 * MAXPC + mid] > ki) lo = mid + 1; else hi = mid;
            }
            r += lo;
        }
        if (r < MAXPI) {
            int flat = (int)(~(u32)ki);
            int pos = flat - cc * N;
            int oi = order[cc * N + pos];
            float4 bb = decode_one(rpn, deltas, oi);
            out[r * 4 + 0] = bb.x;
            out[r * 4 + 1] = bb.y;
            out[r * 4 + 2] = bb.z;
            out[r * 4 + 3] = bb.w;
            out[4 * MAXPI + r] = (float)cc;
        }
    }
    // rare path: M<100 -> fill with NEG entries, smallest flat first (class 0
    // positions; among pos 0..149 at most 50 kept -> >=100 invalid slots).
    if (tid == 0 && M < MAXPI) {
        int m = M;
        int cnt0 = scnt[0];
        for (int pos = 0; pos < 150 && m < MAXPI; pos++) {
            bool validp = false;
            for (int k = 0; k < cnt0; k++)
                if (keep_pos[k] == pos) { validp = true; break; }
            if (!validp) {
                int oi = order[pos];
                float4 bb = decode_one(rpn, deltas, oi);
                out[m * 4 + 0] = bb.x;
                out[m * 4 + 1] = bb.y;
                out[m * 4 + 2] = bb.z;
                out[m * 4 + 3] = bb.w;
                out[4 * MAXPI + m] = 0.0f;
                m++;
            }
        }
    }
}

extern "C" void kernel_launch(void* const* d_in, const int* in_sizes, int n_in,
                              void* d_out, int out_size, void* d_ws, size_t ws_size,
                              hipStream_t stream) {
    const float* rpn    = (const float*)d_in[0];  // [2000,4]
    const float* deltas = (const float*)d_in[1];  // [2000,4]
    const float* score  = (const float*)d_in[2];  // [2000,21]
    float* out = (float*)d_out;                   // 400 box floats + 100 cls

    char* ws = (char*)d_ws;
    int*   order    = (int*)(ws);                 // 168000 B
    u64*   candk    = (u64*)(ws + 168000);        // 8400 B (8-aligned)
    int*   keep_pos = (int*)(ws + 176400);        // 4200 B
    int*   keep_cnt = (int*)(ws + 180600);        // 84 B

    sort_kernel<<<dim3(NCLS, 32), 256, 0, stream>>>(score, order);
    nms_kernel<<<NCLS, 64, 0, stream>>>(rpn, deltas, order, score,
                                        keep_pos, keep_cnt, candk);
    topk_kernel<<<1, 1024, 0, stream>>>(rpn, deltas, order,
                                        keep_pos, keep_cnt, candk, out);
}